// Round 12
// baseline (1282.797 us; speedup 1.0000x reference)
//
#pragma clang fp contract(off)
#include <hip/hip_runtime.h>
#include <math.h>

// MotionTrackingLK: bitwise emulation of an all-f32 numpy reference.
// One wave per track; 2048 tracks; 15 steps x 5 LK iterations.
// f32 elementwise everywhere (contract off, single-op stmts);
// einsum reductions = ascending-k scalar single-accumulator RMW
// (nditer: contracted k next-outer, i/j innermost);
// Sobel conv = windows+einsum GROWINNER 9-run, npyv SSE3:
//   lanes c_l = t_l + t_{l+4}; hsum (c0+c1)+(c2+c3); + t8 tail.

#define WINSZ 21
#define KPTS  441
#define NPT   7      // points per lane: lanes 0..62 own 7 consecutive k

struct SB {
  float fw[23][24];     // first window + zero ring (SAME conv padding)
  float g2[KPTS][2];    // Ix, Iy
  float t2[KPTS][2];    // Ix*ww, Iy*ww
  float bv[KPTS];       // (first-second)*ww
};

__device__ __forceinline__ float bilinf(const float* __restrict__ F,
                                        float x, float y) {
  #pragma clang fp contract(off)
  float fx = floorf(x), fy = floorf(y);
  float x0 = fminf(fmaxf(fx, 0.0f), 511.0f);
  float x1a = fx + 1.0f;
  float x1 = fminf(fmaxf(x1a, 0.0f), 511.0f);
  float y0 = fminf(fmaxf(fy, 0.0f), 511.0f);
  float y1a = fy + 1.0f;
  float y1 = fminf(fmaxf(y1a, 0.0f), 511.0f);
  float dy1 = y1 - y, dx1 = x1 - x, dy0 = y - y0, dx0 = x - x0;
  float wa = dy1 * dx1;
  float wb = dy1 * dx0;
  float wc = dy0 * dx1;
  float wd = dy0 * dx0;
  int jx0 = (int)x0, jx1 = (int)x1, jy0 = (int)y0, jy1 = (int)y1;
  float Ia = F[jy0 * 512 + jx0];
  float Ib = F[jy0 * 512 + jx1];
  float Ic = F[jy1 * 512 + jx0];
  float Id = F[jy1 * 512 + jx1];
  float pA = wa * Ia;
  float pB = wb * Ib;
  float pC = wc * Ic;
  float pD = wd * Id;
  float s = pA + pB;
  s = s + pC;
  s = s + pD;
  return s;
}

__global__ __launch_bounds__(64) void lk_track(
    const float* __restrict__ track_locs,  // (B, NT, 2)
    const float* __restrict__ imgs,        // (B, S, 512, 512, 1)
    float* __restrict__ out)               // (B, NT, S, 2)
{
  #pragma clang fp contract(off)
  __shared__ SB S;
  const float CRF = (float)(512.0 / 21.0);  // np.float32(W/WIN)
  const int SS = 16, HW = 512 * 512;

  const int tr   = blockIdx.x;   // b*256 + n
  const int b    = tr >> 8;
  const int lane = threadIdx.x;

  for (int i = lane; i < 23 * 24; i += 64) (&S.fw[0][0])[i] = 0.0f;

  const bool act = (lane < 63);
  int   rr[NPT], cc[NPT];
  float gxv[NPT], gyv[NPT], wwv[NPT];
  const double gnorm = 1.0 / (2.0 * sqrt(2.0 * 3.141592653589793));
#pragma unroll
  for (int j = 0; j < NPT; j++) {
    int k = lane * NPT + j;
    if (k >= KPTS) k = 0;                  // lane 63: dummy (never stored)
    int r = k / WINSZ, c = k % WINSZ;
    rr[j] = r; cc[j] = c;
    // f32(np.linspace f64): i*0.1-1.0 in f64 (endpoint exact), cast f32
    gxv[j] = (c == 20) ? 1.0f : (float)((double)c * 0.1 - 1.0);
    gyv[j] = (r == 20) ? 1.0f : (float)((double)r * 0.1 - 1.0);
    // ww: f64 formula exactly as numpy, then f32 cast
    double dd = sqrt((double)((c - 10) * (c - 10) + (r - 10) * (r - 10)));
    double q  = dd / 2.0;
    wwv[j] = (float)(gnorm * exp(-0.5 * (q * q)));
  }

  // init = tl*cr + cr, f32 mul then f32 add, no FMA
  const float* tl = track_locs + (size_t)tr * 2;
  float mx = tl[0] * CRF; float initx = mx + CRF;
  float my = tl[1] * CRF; float inity = my + CRF;

  // per-point sampler state, f32, carried across steps exactly like numpy
  float sx[NPT], sy[NPT];
#pragma unroll
  for (int j = 0; j < NPT; j++) { sx[j] = initx + gxv[j]; sy[j] = inity + gyv[j]; }

  float px = initx, py = inity;            // pos carry (f32)
  if (lane == 0) {
    float* o = out + (size_t)tr * SS * 2;
    float n0 = initx - CRF; o[0] = n0 / CRF;
    float n1 = inity - CRF; o[1] = n1 / CRF;
  }

  float fv[NPT], scv[NPT];

  for (int t = 0; t < SS - 1; t++) {
    const float* F0 = imgs + ((size_t)b * SS + t) * HW;
    const float* F1 = F0 + HW;

    __syncthreads();                       // prev step's fw/g2/t2 reads done
#pragma unroll
    for (int j = 0; j < NPT; j++) {
      float x = sx[j] * 10.5f, y = sy[j] * 10.5f;
      fv[j]  = bilinf(F0, x, y);
      scv[j] = bilinf(F1, x, y);
      if (act) S.fw[rr[j] + 1][cc[j] + 1] = fv[j];
    }
    __syncthreads();

    // Sobel: npyv 9-run (GROWINNER), SSE3 hsum.
    // taps t0..t8 row-major; c_l = t_l + t_{l+4}; I = ((c0+c1)+(c2+c3)) + t8.
    // Zero-products are bitwise no-ops and dropped. +-1/+-2 products exact.
#pragma unroll
    for (int j = 0; j < NPT; j++) {
      int r = rr[j], c = cc[j];
      float a00 = S.fw[r][c],     a01 = S.fw[r][c + 1],     a02 = S.fw[r][c + 2];
      float a10 = S.fw[r + 1][c],                           a12 = S.fw[r + 1][c + 2];
      float a20 = S.fw[r + 2][c], a21 = S.fw[r + 2][c + 1], a22 = S.fw[r + 2][c + 2];
      // Ix taps: t0=-a00 t1=0 t2=a02 t3=-2a10 | t4=0 t5=2a12 t6=-a20 t7=0 | t8=a22
      float xc0 = -a00;                    // t0+t4
      float xc1 = 2.0f * a12;              // t1+t5
      float xc2 = a02 + (-a20);            // t2+t6
      float xc3 = -2.0f * a10;             // t3+t7
      float xh0 = xc0 + xc1;
      float xh1 = xc2 + xc3;
      float Ix = xh0 + xh1;
      Ix = Ix + a22;                       // tail t8
      // Iy taps: t0=-a00 t1=-2a01 t2=-a02 t3=0 | t4=0 t5=0 t6=a20 t7=2a21 | t8=a22
      float yc0 = -a00;                    // t0+t4
      float yc1 = -2.0f * a01;             // t1+t5
      float yc2 = (-a02) + a20;            // t2+t6
      float yc3 = 2.0f * a21;              // t3+t7
      float yh0 = yc0 + yc1;
      float yh1 = yc2 + yc3;
      float Iy = yh0 + yh1;
      Iy = Iy + a22;                       // tail t8
      if (act) {
        int k = lane * NPT + j;
        S.g2[k][0] = Ix;           S.g2[k][1] = Iy;
        float wx = Ix * wwv[j];    float wy = Iy * wwv[j];
        S.t2[k][0] = wx;           S.t2[k][1] = wy;       // A * ww
      }
    }
    __syncthreads();

    // ATA: ascending-k scalar single-accumulator f32 chains
    float aa = 0.f, bb = 0.f, cN = 0.f, dN = 0.f;
#pragma unroll 7
    for (int k = 0; k < KPTS; k++) {
      float ix = S.g2[k][0], iy = S.g2[k][1];
      float tx = S.t2[k][0], ty = S.t2[k][1];
      float p0 = ix * tx; aa = aa + p0;
      float p1 = ix * ty; bb = bb + p1;
      float p2 = iy * tx; cN = cN + p2;
      float p3 = iy * ty; dN = dN + p3;
    }
    float q0 = aa * dN;
    float q1 = bb * cN;
    float det = q0 - q1;
    det = det + 1e-7f;
    float inv_det = 1.0f / det;

    float svx = 0.f, svy = 0.f;
    for (int it = 0; it < 5; it++) {
      if (it > 0) {
#pragma unroll
        for (int j = 0; j < NPT; j++) {
          float x = sx[j] * 10.5f, y = sy[j] * 10.5f;
          scv[j] = bilinf(F1, x, y);
        }
      }
#pragma unroll
      for (int j = 0; j < NPT; j++) {
        if (act) {
          float d2 = fv[j] - scv[j];            // == -(second-first) bitwise
          float bw = d2 * wwv[j];
          S.bv[lane * NPT + j] = bw;
        }
      }
      __syncthreads();
      // ATb: ascending-k scalar, single f32 accumulator each
      float s0 = 0.f, s1 = 0.f;
#pragma unroll 7
      for (int k = 0; k < KPTS; k++) {
        float bk = S.bv[k];
        float u0 = S.g2[k][0] * bk; s0 = s0 + u0;
        float u1 = S.g2[k][1] * bk; s1 = s1 + u1;
      }
      float e0 = dN * s0;
      float e1 = bb * s1;
      float numx = e0 - e1;
      float vx = inv_det * numx;
      float f0 = (-cN) * s0;
      float f1 = aa * s1;
      float numy = f0 + f1;
      float vy = inv_det * numy;
#pragma unroll
      for (int j = 0; j < NPT; j++) { sx[j] = sx[j] + vx; sy[j] = sy[j] + vy; }
      if (it == 0) { svx = vx;       svy = vy; }
      else         { svx = svx + vx; svy = svy + vy; }
      __syncthreads();                   // bv reads done before next write
    }

    px = px + svx; py = py + svy;        // pos = prev + sum_v (f32)
    if (lane == 0) {
      float* o = out + ((size_t)tr * SS + (t + 1)) * 2;
      float n0 = px - CRF; o[0] = n0 / CRF;
      float n1 = py - CRF; o[1] = n1 / CRF;
    }
  }
}

extern "C" void kernel_launch(void* const* d_in, const int* in_sizes, int n_in,
                              void* d_out, int out_size, void* d_ws, size_t ws_size,
                              hipStream_t stream) {
  const float* tl   = (const float*)d_in[0];  // (8,256,2) f32
  const float* imgs = (const float*)d_in[1];  // (8,16,512,512,1) f32
  float* o          = (float*)d_out;          // 65536 f32
  lk_track<<<dim3(2048), dim3(64), 0, stream>>>(tl, imgs, o);
}

// Round 13
// 463.909 us; speedup vs baseline: 2.7652x; 2.7652x over previous
//
#pragma clang fp contract(off)
#include <hip/hip_runtime.h>
#include <math.h>

// MotionTrackingLK — PASSING numerics (R12 config), optimized execution.
// Numerics contract (frozen, bitwise): f32 everywhere, contract off,
// single-op statements; einsums = ascending-k scalar single-accumulator
// chains; Sobel = npyv SSE3 9-run (c_l = t_l + t_{l+4}; (c0+c1)+(c2+c3); +t8);
// bilinear left-to-right; per-point f32 sampler carry.
// Perf changes (bitwise-neutral): products hoisted to owning lanes
// (parallel), serial chains reduced to read+add, 4 ATA chains split across
// 4 lane-groups / 2 ATb chains across 2 lane-halves, shfl broadcast.

#define WINSZ 21
#define KPTS  441
#define NPT   7      // points per lane: lanes 0..62 own 7 consecutive k

struct SB {
  float fw[23][24];      // 2208 B: first window + zero ring (16B-mult)
  float pq[KPTS][4];     // 7056 B: ATA products {Ix*tx, Ix*ty, Iy*tx, Iy*ty}
  float ub[KPTS][2];     // 3528 B: ATb products {Ix*bw, Iy*bw}
};

__device__ __forceinline__ float bilinf(const float* __restrict__ F,
                                        float x, float y) {
  #pragma clang fp contract(off)
  float fx = floorf(x), fy = floorf(y);
  float x0 = fminf(fmaxf(fx, 0.0f), 511.0f);
  float x1a = fx + 1.0f;
  float x1 = fminf(fmaxf(x1a, 0.0f), 511.0f);
  float y0 = fminf(fmaxf(fy, 0.0f), 511.0f);
  float y1a = fy + 1.0f;
  float y1 = fminf(fmaxf(y1a, 0.0f), 511.0f);
  float dy1 = y1 - y, dx1 = x1 - x, dy0 = y - y0, dx0 = x - x0;
  float wa = dy1 * dx1;
  float wb = dy1 * dx0;
  float wc = dy0 * dx1;
  float wd = dy0 * dx0;
  int jx0 = (int)x0, jx1 = (int)x1, jy0 = (int)y0, jy1 = (int)y1;
  float Ia = F[jy0 * 512 + jx0];
  float Ib = F[jy0 * 512 + jx1];
  float Ic = F[jy1 * 512 + jx0];
  float Id = F[jy1 * 512 + jx1];
  float pA = wa * Ia;
  float pB = wb * Ib;
  float pC = wc * Ic;
  float pD = wd * Id;
  float s = pA + pB;
  s = s + pC;
  s = s + pD;
  return s;
}

__global__ __launch_bounds__(64) void lk_track(
    const float* __restrict__ track_locs,  // (B, NT, 2)
    const float* __restrict__ imgs,        // (B, S, 512, 512, 1)
    float* __restrict__ out)               // (B, NT, S, 2)
{
  #pragma clang fp contract(off)
  __shared__ SB S;
  const float CRF = (float)(512.0 / 21.0);  // np.float32(W/WIN)
  const int SS = 16, HW = 512 * 512;

  const int tr   = blockIdx.x;   // b*256 + n
  const int b    = tr >> 8;
  const int lane = threadIdx.x;

  for (int i = lane; i < 23 * 24; i += 64) (&S.fw[0][0])[i] = 0.0f;

  const bool act = (lane < 63);
  int   rr[NPT], cc[NPT];
  float gxv[NPT], gyv[NPT], wwv[NPT];
  const double gnorm = 1.0 / (2.0 * sqrt(2.0 * 3.141592653589793));
#pragma unroll
  for (int j = 0; j < NPT; j++) {
    int k = lane * NPT + j;
    if (k >= KPTS) k = 0;                  // lane 63: dummy (never stored)
    int r = k / WINSZ, c = k % WINSZ;
    rr[j] = r; cc[j] = c;
    gxv[j] = (c == 20) ? 1.0f : (float)((double)c * 0.1 - 1.0);
    gyv[j] = (r == 20) ? 1.0f : (float)((double)r * 0.1 - 1.0);
    double dd = sqrt((double)((c - 10) * (c - 10) + (r - 10) * (r - 10)));
    double q  = dd / 2.0;
    wwv[j] = (float)(gnorm * exp(-0.5 * (q * q)));
  }

  // init = tl*cr + cr, f32 mul then f32 add, no FMA
  const float* tl = track_locs + (size_t)tr * 2;
  float mx = tl[0] * CRF; float initx = mx + CRF;
  float my = tl[1] * CRF; float inity = my + CRF;

  float sx[NPT], sy[NPT];
#pragma unroll
  for (int j = 0; j < NPT; j++) { sx[j] = initx + gxv[j]; sy[j] = inity + gyv[j]; }

  float px = initx, py = inity;            // pos carry (f32)
  if (lane == 0) {
    float* o = out + (size_t)tr * SS * 2;
    float n0 = initx - CRF; o[0] = n0 / CRF;
    float n1 = inity - CRF; o[1] = n1 / CRF;
  }

  const int grp4 = lane >> 4;              // 0..3: ATA component group
  const int grp2 = lane >> 5;              // 0..1: ATb component group
  const float* paBase = &S.pq[0][grp4];    // stride 4 floats
  const float* ubBase = &S.ub[0][grp2];    // stride 2 floats

  float fv[NPT], scv[NPT], ixv[NPT], iyv[NPT];

  for (int t = 0; t < SS - 1; t++) {
    const float* F0 = imgs + ((size_t)b * SS + t) * HW;
    const float* F1 = F0 + HW;

    __syncthreads();                       // prev step's fw/pq reads done
#pragma unroll
    for (int j = 0; j < NPT; j++) {
      float x = sx[j] * 10.5f, y = sy[j] * 10.5f;
      fv[j]  = bilinf(F0, x, y);
      scv[j] = bilinf(F1, x, y);
      if (act) S.fw[rr[j] + 1][cc[j] + 1] = fv[j];
    }
    __syncthreads();

    // Sobel (npyv SSE3 9-run order) + ATA products, computed by OWNING lane
    // (bitwise identical values to the redundant version).
#pragma unroll
    for (int j = 0; j < NPT; j++) {
      int r = rr[j], c = cc[j];
      float a00 = S.fw[r][c],     a01 = S.fw[r][c + 1],     a02 = S.fw[r][c + 2];
      float a10 = S.fw[r + 1][c],                           a12 = S.fw[r + 1][c + 2];
      float a20 = S.fw[r + 2][c], a21 = S.fw[r + 2][c + 1], a22 = S.fw[r + 2][c + 2];
      float xc0 = -a00;
      float xc1 = 2.0f * a12;
      float xc2 = a02 + (-a20);
      float xc3 = -2.0f * a10;
      float xh0 = xc0 + xc1;
      float xh1 = xc2 + xc3;
      float Ix = xh0 + xh1;
      Ix = Ix + a22;
      float yc0 = -a00;
      float yc1 = -2.0f * a01;
      float yc2 = (-a02) + a20;
      float yc3 = 2.0f * a21;
      float yh0 = yc0 + yc1;
      float yh1 = yc2 + yc3;
      float Iy = yh0 + yh1;
      Iy = Iy + a22;
      ixv[j] = Ix; iyv[j] = Iy;
      if (act) {
        int k = lane * NPT + j;
        float tx = Ix * wwv[j];            // t2 value (same op as before)
        float ty = Iy * wwv[j];
        float p0 = Ix * tx;                // products, same op order
        float p1 = Ix * ty;
        float p2 = Iy * tx;
        float p3 = Iy * ty;
        float4 pv; pv.x = p0; pv.y = p1; pv.z = p2; pv.w = p3;
        *reinterpret_cast<float4*>(&S.pq[k][0]) = pv;
      }
    }
    __syncthreads();

    // ATA: 4 ascending-k add chains, one per 16-lane group (read+add only).
    float accA = 0.f;
#pragma unroll 21
    for (int k = 0; k < KPTS; k++) {
      float p = paBase[4 * k];
      accA = accA + p;
    }
    float aa = __shfl(accA, 0,  64);
    float bb = __shfl(accA, 16, 64);
    float cN = __shfl(accA, 32, 64);
    float dN = __shfl(accA, 48, 64);
    float q0 = aa * dN;
    float q1 = bb * cN;
    float det = q0 - q1;
    det = det + 1e-7f;
    float inv_det = 1.0f / det;

    float svx = 0.f, svy = 0.f;
    for (int it = 0; it < 5; it++) {
      if (it > 0) {
#pragma unroll
        for (int j = 0; j < NPT; j++) {
          float x = sx[j] * 10.5f, y = sy[j] * 10.5f;
          scv[j] = bilinf(F1, x, y);
        }
      }
      // ATb products by owning lane (same ops/order as before)
#pragma unroll
      for (int j = 0; j < NPT; j++) {
        if (act) {
          int k = lane * NPT + j;
          float d2 = fv[j] - scv[j];
          float bw = d2 * wwv[j];
          float u0 = ixv[j] * bw;
          float u1 = iyv[j] * bw;
          float2 uv; uv.x = u0; uv.y = u1;
          *reinterpret_cast<float2*>(&S.ub[k][0]) = uv;
        }
      }
      __syncthreads();
      // ATb: 2 ascending-k add chains, one per 32-lane half.
      float accB = 0.f;
#pragma unroll 21
      for (int k = 0; k < KPTS; k++) {
        float u = ubBase[2 * k];
        accB = accB + u;
      }
      float s0 = __shfl(accB, 0,  64);
      float s1 = __shfl(accB, 32, 64);
      float e0 = dN * s0;
      float e1 = bb * s1;
      float numx = e0 - e1;
      float vx = inv_det * numx;
      float f0 = (-cN) * s0;
      float f1 = aa * s1;
      float numy = f0 + f1;
      float vy = inv_det * numy;
#pragma unroll
      for (int j = 0; j < NPT; j++) { sx[j] = sx[j] + vx; sy[j] = sy[j] + vy; }
      if (it == 0) { svx = vx;       svy = vy; }
      else         { svx = svx + vx; svy = svy + vy; }
      __syncthreads();                   // ub reads done before next write
    }

    px = px + svx; py = py + svy;        // pos = prev + sum_v (f32)
    if (lane == 0) {
      float* o = out + ((size_t)tr * SS + (t + 1)) * 2;
      float n0 = px - CRF; o[0] = n0 / CRF;
      float n1 = py - CRF; o[1] = n1 / CRF;
    }
  }
}

extern "C" void kernel_launch(void* const* d_in, const int* in_sizes, int n_in,
                              void* d_out, int out_size, void* d_ws, size_t ws_size,
                              hipStream_t stream) {
  const float* tl   = (const float*)d_in[0];  // (8,256,2) f32
  const float* imgs = (const float*)d_in[1];  // (8,16,512,512,1) f32
  float* o          = (float*)d_out;          // 65536 f32
  lk_track<<<dim3(2048), dim3(64), 0, stream>>>(tl, imgs, o);
}